// Round 2
// baseline (1755.300 us; speedup 1.0000x reference)
//
#include <hip/hip_runtime.h>
#include <hip/hip_bf16.h>
#include <math.h>

typedef __hip_bfloat16 bf16;
typedef __attribute__((ext_vector_type(8))) __bf16 bf16x8;
typedef __attribute__((ext_vector_type(4))) float floatx4;

#define CDIM 192
#define N_WINDOWS 2048
#define ATT_SCALE 0.17677669529663687f   // 1/sqrt(32)

__device__ inline float toF(float v) { return v; }
__device__ inline float toF(bf16 v) { return __bfloat162float(v); }

// async global->LDS, 16B per lane; LDS dest = wave-uniform base + lane*16
__device__ inline void gld16(const void* g, void* l) {
    __builtin_amdgcn_global_load_lds((const __attribute__((address_space(1))) uint32_t*)g,
                                     (__attribute__((address_space(3))) uint32_t*)l,
                                     16, 0, 0);
}

// windowed (wi, n, col) -> natural flat element index
__device__ inline long nat_index(int wi, int n, int col) {
    int wb = wi & 15, hb = (wi >> 4) & 15, tb = (wi >> 8) & 3, bb = wi >> 10;
    int t  = tb * 2 + (n >> 6);
    int hh = hb * 8 + ((n >> 3) & 7);
    int w  = wb * 8 + (n & 7);
    return ((((long)(bb * 8 + t)) * 128 + hh) * 128 + w) * CDIM + col;
}

// ---------------------------------------------------------------------------
// Weight pre-conversion f32 -> bf16 (once per launch).
// ---------------------------------------------------------------------------
__launch_bounds__(256)
__global__ void cvt_w_kernel(const float* __restrict__ src, bf16* __restrict__ dst, int n) {
    int i = (blockIdx.x * 256 + threadIdx.x) * 8;
    if (i < n) {
        float4 a = *(const float4*)(src + i);
        float4 b = *(const float4*)(src + i + 4);
        bf16x8 o;
        o[0] = (__bf16)a.x; o[1] = (__bf16)a.y; o[2] = (__bf16)a.z; o[3] = (__bf16)a.w;
        o[4] = (__bf16)b.x; o[5] = (__bf16)b.y; o[6] = (__bf16)b.z; o[7] = (__bf16)b.w;
        *(bf16x8*)(dst + i) = o;
    }
}

// ---------------------------------------------------------------------------
// Relative-position bias, expanded once to [6][128][128] f32 (L2-resident).
// ---------------------------------------------------------------------------
__device__ inline float rel_bias(const float* bt, int h, int n, int m) {
    int tn = n >> 6, hn = (n >> 3) & 7, wn = n & 7;
    int tm = m >> 6, hm = (m >> 3) & 7, wm = m & 7;
    int idx = (tn - tm + 1) * 225 + (hn - hm + 7) * 15 + (wn - wm + 7);
    return bt[idx * 6 + h];
}

__launch_bounds__(256)
__global__ void bias_expand_kernel(const float* __restrict__ bt, float* __restrict__ bias6) {
    int i = blockIdx.x * 256 + threadIdx.x;   // n*128+m, 16384 total
    int n = i >> 7, m = i & 127;
    #pragma unroll
    for (int h = 0; h < 6; ++h)
        bias6[h * 16384 + i] = rel_bias(bt, h, n, m);
}

// ---------------------------------------------------------------------------
// LayerNorm, one wave per row of 192.
// ---------------------------------------------------------------------------
template<bool WINDOWED, typename T>
__launch_bounds__(256)
__global__ void ln_kernel(const T* __restrict__ x, const float* __restrict__ g,
                          const float* __restrict__ bta, bf16* __restrict__ out,
                          int wi_base) {
    int row = blockIdx.x * 4 + (threadIdx.x >> 6);   // slab-local row
    int lane = threadIdx.x & 63;
    long src;
    if (WINDOWED) {
        src = nat_index(wi_base + (row >> 7), row & 127, 0);
    } else {
        src = (long)row * CDIM;
    }
    float v0 = toF(x[src + lane]);
    float v1 = toF(x[src + lane + 64]);
    float v2 = toF(x[src + lane + 128]);
    float s = v0 + v1 + v2;
    float sq = v0 * v0 + v1 * v1 + v2 * v2;
    #pragma unroll
    for (int o = 32; o > 0; o >>= 1) { s += __shfl_xor(s, o); sq += __shfl_xor(sq, o); }
    float mean = s * (1.0f / 192.0f);
    float var  = sq * (1.0f / 192.0f) - mean * mean;
    float rstd = rsqrtf(fmaxf(var, 0.0f) + 1e-5f);
    long dst = (long)row * CDIM;
    out[dst + lane]       = __float2bfloat16((v0 - mean) * rstd * g[lane]       + bta[lane]);
    out[dst + lane + 64]  = __float2bfloat16((v1 - mean) * rstd * g[lane + 64]  + bta[lane + 64]);
    out[dst + lane + 128] = __float2bfloat16((v2 - mean) * rstd * g[lane + 128] + bta[lane + 128]);
}

// ---------------------------------------------------------------------------
// GEMM: C[M,N] = A[M,K](bf16) @ W[N,K]^T(bf16).
// BM=128, BN=64, full K-tile of 192 staged at once via global_load_lds
// (pre-swizzled source, linear LDS dest, XOR-swizzled reads).
// 256 threads = 4 waves, each wave 32x64 (2x4 mfma).  2 blocks/CU.
// ---------------------------------------------------------------------------
template<typename Epi>
__launch_bounds__(256, 2)
__global__ void gemm_bt(const bf16* __restrict__ A, const bf16* __restrict__ Wt,
                        int K, int nb, Epi epi) {
    __shared__ __align__(16) bf16 sA[128 * 192];   // 48 KB, rows of 384 B
    __shared__ __align__(16) bf16 sW[64 * 192];    // 24 KB
    const int tid = threadIdx.x;
    const int lane = tid & 63;
    const int wv = tid >> 6;
    // bijective XCD swizzle (gridDim.x % 8 == 0 in all uses):
    // consecutive swz ids (one A-tile and all its n-blocks) land on one XCD.
    int gid = blockIdx.x;
    int swz = (gid & 7) * (gridDim.x >> 3) + (gid >> 3);
    const int m0 = (swz / nb) * 128;
    const int n0 = (swz % nb) * 64;

    const int colb = lane & 15, quad = lane >> 4;
    floatx4 acc[2][4] = {};

    for (int k0 = 0; k0 < K; k0 += 192) {
        if (k0) __syncthreads();
        #pragma unroll
        for (int i = 0; i < 12; ++i) {           // A tile: 3072 x 16B chunks
            int t = i * 256 + tid;
            int r = t / 24, cb = (t - r * 24) * 16;
            int scb = cb ^ ((r & 7) << 4);       // inverse-swizzled SOURCE
            gld16((const char*)(A + (long)(m0 + r) * K + k0) + scb,
                  (char*)sA + i * 4096 + wv * 1024);
        }
        #pragma unroll
        for (int i = 0; i < 6; ++i) {            // W tile: 1536 x 16B chunks
            int t = i * 256 + tid;
            int r = t / 24, cb = (t - r * 24) * 16;
            int scb = cb ^ ((r & 7) << 4);
            gld16((const char*)(Wt + (long)(n0 + r) * K + k0) + scb,
                  (char*)sW + i * 4096 + wv * 1024);
        }
        __syncthreads();                          // drains vmcnt(0)
        #pragma unroll
        for (int kk = 0; kk < 6; ++kk) {
            bf16x8 aF[2], bF[4];
            int cb = kk * 64 + quad * 16;
            #pragma unroll
            for (int rt = 0; rt < 2; ++rt) {
                int rr = wv * 32 + rt * 16 + colb;
                aF[rt] = *(const bf16x8*)((char*)sA + rr * 384 + (cb ^ ((rr & 7) << 4)));
            }
            #pragma unroll
            for (int ct = 0; ct < 4; ++ct) {
                int rr = ct * 16 + colb;
                bF[ct] = *(const bf16x8*)((char*)sW + rr * 384 + (cb ^ ((rr & 7) << 4)));
            }
            #pragma unroll
            for (int rt = 0; rt < 2; ++rt)
                #pragma unroll
                for (int ct = 0; ct < 4; ++ct)
                    acc[rt][ct] = __builtin_amdgcn_mfma_f32_16x16x32_bf16(aF[rt], bF[ct], acc[rt][ct], 0, 0, 0);
        }
    }
    #pragma unroll
    for (int rt = 0; rt < 2; ++rt)
        #pragma unroll
        for (int r = 0; r < 4; ++r) {
            int row = m0 + wv * 32 + rt * 16 + quad * 4 + r;
            #pragma unroll
            for (int ct = 0; ct < 4; ++ct)
                epi(row, n0 + ct * 16 + colb, acc[rt][ct][r]);
        }
}

// ------------------------------ epilogues ----------------------------------
struct EpiQKV {
    const float* bias; bf16 *q, *k, *v;
    __device__ void operator()(int row, int col, float val) const {
        val += bias[col];
        int wi = row >> 7, n = row & 127;          // slab-local window
        int part = col / 192, rem = col - part * 192;
        int h = rem >> 5, d = rem & 31;
        long base = (long)(wi * 6 + h);
        if (part == 0)      q[(base * 128 + n) * 32 + d] = __float2bfloat16(val * ATT_SCALE);
        else if (part == 1) k[(base * 128 + n) * 32 + d] = __float2bfloat16(val);
        else                v[(base * 32 + d) * 128 + n] = __float2bfloat16(val); // transposed
    }
};

struct EpiProj {   // x2(local, windowed) = attn_proj + x(natural, global)
    const float* bias; const float* x; bf16* x2; int wi_base;
    __device__ void operator()(int row, int col, float val) const {
        val += bias[col];
        long nat = nat_index(wi_base + (row >> 7), row & 127, col);
        x2[(long)row * CDIM + col] = __float2bfloat16(val + x[nat]);
    }
};

struct EpiGelu {
    const float* bias; bf16* h1;
    __device__ void operator()(int row, int col, float val) const {
        val += bias[col];
        float g = 0.5f * val * (1.0f + erff(val * 0.70710678118654752f));
        h1[(long)row * 768 + col] = __float2bfloat16(g);
    }
};

struct EpiOut {    // out(natural, global) = fc2 + x2(local, windowed)
    const float* bias; const bf16* x2; float* out; int wi_base;
    __device__ void operator()(int row, int col, float val) const {
        val += bias[col];
        long nat = nat_index(wi_base + (row >> 7), row & 127, col);
        out[nat] = val + __bfloat162float(x2[(long)row * CDIM + col]);
    }
};

// ---------------------------------------------------------------------------
// Attention: one block per (local window, head). QK^T -> softmax -> PV.
// All LDS tiles XOR-swizzled for conflict-free ds_read_b128.
// ---------------------------------------------------------------------------
__launch_bounds__(256)
__global__ void attn_kernel(const bf16* __restrict__ q, const bf16* __restrict__ k,
                            const bf16* __restrict__ vT, const float* __restrict__ bias6,
                            bf16* __restrict__ out) {
    __shared__ __align__(16) bf16 sQ[128 * 32];    // rows of 64 B, swz (r&6)<<3
    __shared__ __align__(16) bf16 sK[128 * 32];
    __shared__ __align__(16) bf16 sVT[32 * 128];   // rows of 256 B, swz (r&7)<<4
    __shared__ __align__(16) bf16 sP[128 * 128];   // rows of 256 B, swz (r&7)<<4
    const int blk = blockIdx.x;           // wi_local*6 + h
    const int h = blk % 6;
    const int wi = blk / 6;
    const int tid = threadIdx.x, lane = tid & 63, wv = tid >> 6;
    const bf16* qg = q + (long)blk * 4096;
    const bf16* kg = k + (long)blk * 4096;
    const bf16* vg = vT + (long)blk * 4096;
    #pragma unroll
    for (int i = 0; i < 2; ++i) {
        int t = tid + i * 256;                 // 16B-chunk index, [0,512)
        int r = t >> 2, cb = (t & 3) << 4;     // sQ/sK: 4 chunks per 64B row
        int d = r * 64 + (cb ^ ((r & 6) << 3));
        *(uint4*)((char*)sQ + d) = *(const uint4*)(qg + t * 8);
        *(uint4*)((char*)sK + d) = *(const uint4*)(kg + t * 8);
        int rv = t >> 4, cv = (t & 15) << 4;   // sVT: 16 chunks per 256B row
        int dv = rv * 256 + (cv ^ ((rv & 7) << 4));
        *(uint4*)((char*)sVT + dv) = *(const uint4*)(vg + t * 8);
    }
    __syncthreads();

    const int mrow = wv * 32;
    const int colb = lane & 15, quad = lane >> 4;
    floatx4 zero = {0.f, 0.f, 0.f, 0.f};
    floatx4 s[2][8];
    bf16x8 aF[2];
    #pragma unroll
    for (int rt = 0; rt < 2; ++rt) {
        int rr = mrow + rt * 16 + colb;
        aF[rt] = *(const bf16x8*)((char*)sQ + rr * 64 + ((quad * 16) ^ ((rr & 6) << 3)));
    }
    #pragma unroll
    for (int ct = 0; ct < 8; ++ct) {
        int rr = ct * 16 + colb;
        bf16x8 bF = *(const bf16x8*)((char*)sK + rr * 64 + ((quad * 16) ^ ((rr & 6) << 3)));
        #pragma unroll
        for (int rt = 0; rt < 2; ++rt)
            s[rt][ct] = __builtin_amdgcn_mfma_f32_16x16x32_bf16(aF[rt], bF, zero, 0, 0, 0);
    }
    const float* bh = bias6 + h * 16384;
    #pragma unroll
    for (int rt = 0; rt < 2; ++rt) {
        #pragma unroll
        for (int r = 0; r < 4; ++r) {
            int n = mrow + rt * 16 + quad * 4 + r;
            float vals[8];
            float mx = -1e30f;
            #pragma unroll
            for (int ct = 0; ct < 8; ++ct) {
                float v = s[rt][ct][r] + bh[n * 128 + ct * 16 + colb];
                vals[ct] = v; mx = fmaxf(mx, v);
            }
            #pragma unroll
            for (int o = 1; o < 16; o <<= 1) mx = fmaxf(mx, __shfl_xor(mx, o));
            float sum = 0.f;
            #pragma unroll
            for (int ct = 0; ct < 8; ++ct) { vals[ct] = __expf(vals[ct] - mx); sum += vals[ct]; }
            #pragma unroll
            for (int o = 1; o < 16; o <<= 1) sum += __shfl_xor(sum, o);
            float inv = 1.0f / sum;
            #pragma unroll
            for (int ct = 0; ct < 8; ++ct) {
                int cwb = (ct * 16 + colb) * 2;
                *(bf16*)((char*)sP + n * 256 + (cwb ^ ((n & 7) << 4))) =
                    __float2bfloat16(vals[ct] * inv);
            }
        }
    }
    __syncthreads();
    floatx4 o[2][2] = {};
    #pragma unroll
    for (int kk = 0; kk < 4; ++kk) {
        int cbb = kk * 64 + quad * 16;
        bf16x8 aP[2];
        #pragma unroll
        for (int rt = 0; rt < 2; ++rt) {
            int rr = mrow + rt * 16 + colb;
            aP[rt] = *(const bf16x8*)((char*)sP + rr * 256 + (cbb ^ ((rr & 7) << 4)));
        }
        #pragma unroll
        for (int ct = 0; ct < 2; ++ct) {
            int rr = ct * 16 + colb;
            bf16x8 bV = *(const bf16x8*)((char*)sVT + rr * 256 + (cbb ^ ((rr & 7) << 4)));
            #pragma unroll
            for (int rt = 0; rt < 2; ++rt)
                o[rt][ct] = __builtin_amdgcn_mfma_f32_16x16x32_bf16(aP[rt], bV, o[rt][ct], 0, 0, 0);
        }
    }
    #pragma unroll
    for (int rt = 0; rt < 2; ++rt)
        #pragma unroll
        for (int ct = 0; ct < 2; ++ct)
            #pragma unroll
            for (int r = 0; r < 4; ++r) {
                int n = mrow + rt * 16 + quad * 4 + r;
                out[((long)(wi * 128 + n)) * CDIM + h * 32 + ct * 16 + colb] =
                    __float2bfloat16(o[rt][ct][r]);
            }
}

// ---------------------------------------------------------------------------
extern "C" void kernel_launch(void* const* d_in, const int* in_sizes, int n_in,
                              void* d_out, int out_size, void* d_ws, size_t ws_size,
                              hipStream_t stream) {
    const float* x      = (const float*)d_in[0];
    const float* n1g    = (const float*)d_in[1];
    const float* n1b    = (const float*)d_in[2];
    const float* qkv_w  = (const float*)d_in[3];
    const float* qkv_b  = (const float*)d_in[4];
    const float* btab   = (const float*)d_in[5];
    const float* proj_w = (const float*)d_in[6];
    const float* proj_b = (const float*)d_in[7];
    const float* n2g    = (const float*)d_in[8];
    const float* n2b    = (const float*)d_in[9];
    const float* fc1_w  = (const float*)d_in[10];
    const float* fc1_b  = (const float*)d_in[11];
    const float* fc2_w  = (const float*)d_in[12];
    const float* fc2_b  = (const float*)d_in[13];
    float* outp = (float*)d_out;

    char* ws = (char*)d_ws;

    // ---- bf16 weight copies + expanded bias table at front of workspace ---
    const int NQKV = 576 * 192, NPROJ = 192 * 192, NFC1 = 768 * 192, NFC2 = 192 * 768;
    bf16* qkvW = (bf16*)ws;
    bf16* projW = qkvW + NQKV;
    bf16* fc1W = projW + NPROJ;
    bf16* fc2W = fc1W + NFC1;
    const size_t WBYTES = (size_t)(NQKV + NPROJ + NFC1 + NFC2) * 2;  // 884736
    float* bias6 = (float*)(ws + WBYTES);                            // 6*128*128 f32
    const size_t BBYTES = 6UL * 128 * 128 * 4;                       // 393216

    cvt_w_kernel<<<NQKV / 2048, 256, 0, stream>>>(qkv_w, qkvW, NQKV);
    cvt_w_kernel<<<NPROJ / 2048, 256, 0, stream>>>(proj_w, projW, NPROJ);
    cvt_w_kernel<<<NFC1 / 2048, 256, 0, stream>>>(fc1_w, fc1W, NFC1);
    cvt_w_kernel<<<NFC2 / 2048, 256, 0, stream>>>(fc2_w, fc2W, NFC2);
    bias_expand_kernel<<<64, 256, 0, stream>>>(btab, bias6);

    // ---- slab sizing: keep all intermediates L3-resident ------------------
    const size_t per_win = 6UL * 128 * 192 * 2;   // 294912 B per window
    size_t avail = ws_size > WBYTES + BBYTES ? ws_size - WBYTES - BBYTES : 0;
    int S = 512;
    while (S > 64 && (size_t)S * per_win > avail) S >>= 1;

    char* slots = ws + WBYTES + BBYTES;
    const size_t SLOT = (size_t)S * 128 * CDIM * 2;   // bytes per slot
    bf16* bufA = (bf16*)(slots);               // ln1 out -> attn_out -> xn2
    bf16* qb   = (bf16*)(slots + SLOT);        // q -> x2
    bf16* kb   = (bf16*)(slots + 2 * SLOT);    // k -> h1 (4 slots: 2..5)
    bf16* vb   = (bf16*)(slots + 3 * SLOT);    // v (transposed)
    bf16* x2   = qb;
    bf16* h1   = kb;

    for (int s0 = 0; s0 < N_WINDOWS; s0 += S) {
        ln_kernel<true, float><<<S * 32, 256, 0, stream>>>(x, n1g, n1b, bufA, s0);
        gemm_bt<EpiQKV><<<S * 9, 256, 0, stream>>>(bufA, qkvW, 192, 9, EpiQKV{qkv_b, qb, kb, vb});
        attn_kernel<<<S * 6, 256, 0, stream>>>(qb, kb, vb, bias6, bufA);
        gemm_bt<EpiProj><<<S * 3, 256, 0, stream>>>(bufA, projW, 192, 3, EpiProj{proj_b, x, x2, s0});
        ln_kernel<false, bf16><<<S * 32, 256, 0, stream>>>(x2, n2g, n2b, bufA, 0);
        gemm_bt<EpiGelu><<<S * 12, 256, 0, stream>>>(bufA, fc1W, 192, 12, EpiGelu{fc1_b, h1});
        gemm_bt<EpiOut><<<S * 3, 256, 0, stream>>>(h1, fc2W, 768, 3, EpiOut{fc2_b, x2, outp, s0});
    }
}

// Round 3
// 1490.659 us; speedup vs baseline: 1.1775x; 1.1775x over previous
//
#include <hip/hip_runtime.h>
#include <hip/hip_bf16.h>
#include <math.h>

typedef __hip_bfloat16 bf16;
typedef __attribute__((ext_vector_type(8))) __bf16 bf16x8;
typedef __attribute__((ext_vector_type(4))) float floatx4;

#define CDIM 192
#define N_WINDOWS 2048
#define ATT_SCALE 0.17677669529663687f   // 1/sqrt(32)

__device__ inline float toF(float v) { return v; }
__device__ inline float toF(bf16 v) { return __bfloat162float(v); }

// async global->LDS, 16B per lane; LDS dest = wave-uniform base + lane*16
__device__ inline void gld16(const void* g, void* l) {
    __builtin_amdgcn_global_load_lds((const __attribute__((address_space(1))) uint32_t*)g,
                                     (__attribute__((address_space(3))) uint32_t*)l,
                                     16, 0, 0);
}

// windowed (wi, n, col) -> natural flat element index
__device__ inline long nat_index(int wi, int n, int col) {
    int wb = wi & 15, hb = (wi >> 4) & 15, tb = (wi >> 8) & 3, bb = wi >> 10;
    int t  = tb * 2 + (n >> 6);
    int hh = hb * 8 + ((n >> 3) & 7);
    int w  = wb * 8 + (n & 7);
    return ((((long)(bb * 8 + t)) * 128 + hh) * 128 + w) * CDIM + col;
}

// ---------------------------------------------------------------------------
// Weight pre-conversion f32 -> bf16 (once per launch).
// ---------------------------------------------------------------------------
__launch_bounds__(256)
__global__ void cvt_w_kernel(const float* __restrict__ src, bf16* __restrict__ dst, int n) {
    int i = (blockIdx.x * 256 + threadIdx.x) * 8;
    if (i < n) {
        float4 a = *(const float4*)(src + i);
        float4 b = *(const float4*)(src + i + 4);
        bf16x8 o;
        o[0] = (__bf16)a.x; o[1] = (__bf16)a.y; o[2] = (__bf16)a.z; o[3] = (__bf16)a.w;
        o[4] = (__bf16)b.x; o[5] = (__bf16)b.y; o[6] = (__bf16)b.z; o[7] = (__bf16)b.w;
        *(bf16x8*)(dst + i) = o;
    }
}

// ---------------------------------------------------------------------------
// Relative-position bias, expanded once to [6][128][128] f32 (L2-resident).
// ---------------------------------------------------------------------------
__device__ inline float rel_bias(const float* bt, int h, int n, int m) {
    int tn = n >> 6, hn = (n >> 3) & 7, wn = n & 7;
    int tm = m >> 6, hm = (m >> 3) & 7, wm = m & 7;
    int idx = (tn - tm + 1) * 225 + (hn - hm + 7) * 15 + (wn - wm + 7);
    return bt[idx * 6 + h];
}

__launch_bounds__(256)
__global__ void bias_expand_kernel(const float* __restrict__ bt, float* __restrict__ bias6) {
    int i = blockIdx.x * 256 + threadIdx.x;   // n*128+m, 16384 total
    int n = i >> 7, m = i & 127;
    #pragma unroll
    for (int h = 0; h < 6; ++h)
        bias6[h * 16384 + i] = rel_bias(bt, h, n, m);
}

// ---------------------------------------------------------------------------
// LayerNorm, one wave per row of 192.
// ---------------------------------------------------------------------------
template<bool WINDOWED, typename T>
__launch_bounds__(256)
__global__ void ln_kernel(const T* __restrict__ x, const float* __restrict__ g,
                          const float* __restrict__ bta, bf16* __restrict__ out,
                          int wi_base) {
    int row = blockIdx.x * 4 + (threadIdx.x >> 6);   // slab-local row
    int lane = threadIdx.x & 63;
    long src;
    if (WINDOWED) {
        src = nat_index(wi_base + (row >> 7), row & 127, 0);
    } else {
        src = (long)row * CDIM;
    }
    float v0 = toF(x[src + lane]);
    float v1 = toF(x[src + lane + 64]);
    float v2 = toF(x[src + lane + 128]);
    float s = v0 + v1 + v2;
    float sq = v0 * v0 + v1 * v1 + v2 * v2;
    #pragma unroll
    for (int o = 32; o > 0; o >>= 1) { s += __shfl_xor(s, o); sq += __shfl_xor(sq, o); }
    float mean = s * (1.0f / 192.0f);
    float var  = sq * (1.0f / 192.0f) - mean * mean;
    float rstd = rsqrtf(fmaxf(var, 0.0f) + 1e-5f);
    long dst = (long)row * CDIM;
    out[dst + lane]       = __float2bfloat16((v0 - mean) * rstd * g[lane]       + bta[lane]);
    out[dst + lane + 64]  = __float2bfloat16((v1 - mean) * rstd * g[lane + 64]  + bta[lane + 64]);
    out[dst + lane + 128] = __float2bfloat16((v2 - mean) * rstd * g[lane + 128] + bta[lane + 128]);
}

// ---------------------------------------------------------------------------
// GEMM: C[M,N] = A[M,K](bf16) @ W[N,K]^T(bf16).
// BM=128, BN=64, BK=64 double-buffered (48 KB LDS -> 3 blocks/CU).
// 2-phase pipeline: STAGE(next) issued before compute(cur); one barrier/step.
// global_load_lds staging with pre-swizzled source + XOR-swizzled reads.
// 256 threads = 4 waves, each wave 32x64 (2x4 mfma).
// ---------------------------------------------------------------------------
template<typename Epi>
__launch_bounds__(256, 3)
__global__ void gemm_bt(const bf16* __restrict__ A, const bf16* __restrict__ Wt,
                        int K, int nb, Epi epi) {
    __shared__ __align__(16) bf16 sA[2][128 * 64];   // 16 KB each, rows of 128 B
    __shared__ __align__(16) bf16 sW[2][64 * 64];    // 8 KB each
    const int tid = threadIdx.x;
    const int lane = tid & 63;
    const int wv = tid >> 6;
    // bijective XCD swizzle (gridDim.x % 8 == 0 in all uses):
    // each XCD gets a contiguous swz chunk -> A-tile n-blocks share its L2.
    int gid = blockIdx.x;
    int swz = (gid & 7) * (gridDim.x >> 3) + (gid >> 3);
    const int m0 = (swz / nb) * 128;
    const int n0 = (swz % nb) * 64;
    const int colb = lane & 15, quad = lane >> 4;

    floatx4 acc[2][4] = {};
    const int nt = K >> 6;

    // stage k-tile t into buffer b: A 1024 chunks (4/thread), W 512 (2/thread)
    #define STAGE(b, k0)                                                        \
        {                                                                       \
            _Pragma("unroll")                                                   \
            for (int i = 0; i < 4; ++i) {                                       \
                int c = i * 256 + tid;                                          \
                int r = c >> 3, cc = (c & 7) << 4;                              \
                int scb = cc ^ ((r & 7) << 4);                                  \
                gld16((const char*)(A + (long)(m0 + r) * K + (k0)) + scb,       \
                      (char*)sA[b] + i * 4096 + wv * 1024);                     \
            }                                                                   \
            _Pragma("unroll")                                                   \
            for (int i = 0; i < 2; ++i) {                                       \
                int c = i * 256 + tid;                                          \
                int r = c >> 3, cc = (c & 7) << 4;                              \
                int scb = cc ^ ((r & 7) << 4);                                  \
                gld16((const char*)(Wt + (long)(n0 + r) * K + (k0)) + scb,      \
                      (char*)sW[b] + i * 4096 + wv * 1024);                     \
            }                                                                   \
        }

    STAGE(0, 0);
    __syncthreads();                       // drains vmcnt(0): buf0 ready
    for (int t = 0; t < nt; ++t) {
        int cur = t & 1;
        if (t + 1 < nt) STAGE(cur ^ 1, (t + 1) << 6);   // prefetch next tile
        #pragma unroll
        for (int kk = 0; kk < 2; ++kk) {
            bf16x8 aF[2], bF[4];
            int cb = kk * 64 + quad * 16;
            #pragma unroll
            for (int rt = 0; rt < 2; ++rt) {
                int rr = wv * 32 + rt * 16 + colb;
                aF[rt] = *(const bf16x8*)((char*)sA[cur] + rr * 128 + (cb ^ ((rr & 7) << 4)));
            }
            #pragma unroll
            for (int ct = 0; ct < 4; ++ct) {
                int rr = ct * 16 + colb;
                bF[ct] = *(const bf16x8*)((char*)sW[cur] + rr * 128 + (cb ^ ((rr & 7) << 4)));
            }
            #pragma unroll
            for (int rt = 0; rt < 2; ++rt)
                #pragma unroll
                for (int ct = 0; ct < 4; ++ct)
                    acc[rt][ct] = __builtin_amdgcn_mfma_f32_16x16x32_bf16(aF[rt], bF[ct], acc[rt][ct], 0, 0, 0);
        }
        if (t + 1 < nt) __syncthreads();   // drains prefetch; protects buffers
    }
    #undef STAGE

    #pragma unroll
    for (int rt = 0; rt < 2; ++rt)
        #pragma unroll
        for (int r = 0; r < 4; ++r) {
            int row = m0 + wv * 32 + rt * 16 + quad * 4 + r;
            #pragma unroll
            for (int ct = 0; ct < 4; ++ct)
                epi(row, n0 + ct * 16 + colb, acc[rt][ct][r]);
        }
}

// ------------------------------ epilogues ----------------------------------
struct EpiQKV {
    const float* bias; bf16 *q, *k, *v;
    __device__ void operator()(int row, int col, float val) const {
        val += bias[col];
        int wi = row >> 7, n = row & 127;          // slab-local window
        int part = col / 192, rem = col - part * 192;
        int h = rem >> 5, d = rem & 31;
        long base = (long)(wi * 6 + h);
        if (part == 0)      q[(base * 128 + n) * 32 + d] = __float2bfloat16(val * ATT_SCALE);
        else if (part == 1) k[(base * 128 + n) * 32 + d] = __float2bfloat16(val);
        else                v[(base * 32 + d) * 128 + n] = __float2bfloat16(val); // transposed
    }
};

struct EpiProj {   // x2(local, windowed) = attn_proj + x(natural, global)
    const float* bias; const float* x; bf16* x2; int wi_base;
    __device__ void operator()(int row, int col, float val) const {
        val += bias[col];
        long nat = nat_index(wi_base + (row >> 7), row & 127, col);
        x2[(long)row * CDIM + col] = __float2bfloat16(val + x[nat]);
    }
};

struct EpiGelu {
    const float* bias; bf16* h1;
    __device__ void operator()(int row, int col, float val) const {
        val += bias[col];
        float g = 0.5f * val * (1.0f + erff(val * 0.70710678118654752f));
        h1[(long)row * 768 + col] = __float2bfloat16(g);
    }
};

struct EpiOut {    // out(natural, global) = fc2 + x2(local, windowed)
    const float* bias; const bf16* x2; float* out; int wi_base;
    __device__ void operator()(int row, int col, float val) const {
        val += bias[col];
        long nat = nat_index(wi_base + (row >> 7), row & 127, col);
        out[nat] = val + __bfloat162float(x2[(long)row * CDIM + col]);
    }
};

// ---------------------------------------------------------------------------
// Attention: one block per (local window, head). QK^T -> softmax -> PV.
// All LDS tiles XOR-swizzled for conflict-free ds_read_b128.
// ---------------------------------------------------------------------------
__launch_bounds__(256)
__global__ void attn_kernel(const bf16* __restrict__ q, const bf16* __restrict__ k,
                            const bf16* __restrict__ vT, const float* __restrict__ bias6,
                            bf16* __restrict__ out) {
    __shared__ __align__(16) bf16 sQ[128 * 32];    // rows of 64 B, swz (r&6)<<3
    __shared__ __align__(16) bf16 sK[128 * 32];
    __shared__ __align__(16) bf16 sVT[32 * 128];   // rows of 256 B, swz (r&7)<<4
    __shared__ __align__(16) bf16 sP[128 * 128];   // rows of 256 B, swz (r&7)<<4
    const int blk = blockIdx.x;           // wi_local*6 + h
    const int h = blk % 6;
    const int wi = blk / 6;
    const int tid = threadIdx.x, lane = tid & 63, wv = tid >> 6;
    const bf16* qg = q + (long)blk * 4096;
    const bf16* kg = k + (long)blk * 4096;
    const bf16* vg = vT + (long)blk * 4096;
    #pragma unroll
    for (int i = 0; i < 2; ++i) {
        int t = tid + i * 256;                 // 16B-chunk index, [0,512)
        int r = t >> 2, cb = (t & 3) << 4;     // sQ/sK: 4 chunks per 64B row
        int d = r * 64 + (cb ^ ((r & 6) << 3));
        *(uint4*)((char*)sQ + d) = *(const uint4*)(qg + t * 8);
        *(uint4*)((char*)sK + d) = *(const uint4*)(kg + t * 8);
        int rv = t >> 4, cv = (t & 15) << 4;   // sVT: 16 chunks per 256B row
        int dv = rv * 256 + (cv ^ ((rv & 7) << 4));
        *(uint4*)((char*)sVT + dv) = *(const uint4*)(vg + t * 8);
    }
    __syncthreads();

    const int mrow = wv * 32;
    const int colb = lane & 15, quad = lane >> 4;
    floatx4 zero = {0.f, 0.f, 0.f, 0.f};
    floatx4 s[2][8];
    bf16x8 aF[2];
    #pragma unroll
    for (int rt = 0; rt < 2; ++rt) {
        int rr = mrow + rt * 16 + colb;
        aF[rt] = *(const bf16x8*)((char*)sQ + rr * 64 + ((quad * 16) ^ ((rr & 6) << 3)));
    }
    #pragma unroll
    for (int ct = 0; ct < 8; ++ct) {
        int rr = ct * 16 + colb;
        bf16x8 bF = *(const bf16x8*)((char*)sK + rr * 64 + ((quad * 16) ^ ((rr & 6) << 3)));
        #pragma unroll
        for (int rt = 0; rt < 2; ++rt)
            s[rt][ct] = __builtin_amdgcn_mfma_f32_16x16x32_bf16(aF[rt], bF, zero, 0, 0, 0);
    }
    const float* bh = bias6 + h * 16384;
    #pragma unroll
    for (int rt = 0; rt < 2; ++rt) {
        #pragma unroll
        for (int r = 0; r < 4; ++r) {
            int n = mrow + rt * 16 + quad * 4 + r;
            float vals[8];
            float mx = -1e30f;
            #pragma unroll
            for (int ct = 0; ct < 8; ++ct) {
                float v = s[rt][ct][r] + bh[n * 128 + ct * 16 + colb];
                vals[ct] = v; mx = fmaxf(mx, v);
            }
            #pragma unroll
            for (int o = 1; o < 16; o <<= 1) mx = fmaxf(mx, __shfl_xor(mx, o));
            float sum = 0.f;
            #pragma unroll
            for (int ct = 0; ct < 8; ++ct) { vals[ct] = __expf(vals[ct] - mx); sum += vals[ct]; }
            #pragma unroll
            for (int o = 1; o < 16; o <<= 1) sum += __shfl_xor(sum, o);
            float inv = 1.0f / sum;
            #pragma unroll
            for (int ct = 0; ct < 8; ++ct) {
                int cwb = (ct * 16 + colb) * 2;
                *(bf16*)((char*)sP + n * 256 + (cwb ^ ((n & 7) << 4))) =
                    __float2bfloat16(vals[ct] * inv);
            }
        }
    }
    __syncthreads();
    floatx4 o[2][2] = {};
    #pragma unroll
    for (int kk = 0; kk < 4; ++kk) {
        int cbb = kk * 64 + quad * 16;
        bf16x8 aP[2];
        #pragma unroll
        for (int rt = 0; rt < 2; ++rt) {
            int rr = mrow + rt * 16 + colb;
            aP[rt] = *(const bf16x8*)((char*)sP + rr * 256 + (cbb ^ ((rr & 7) << 4)));
        }
        #pragma unroll
        for (int ct = 0; ct < 2; ++ct) {
            int rr = ct * 16 + colb;
            bf16x8 bV = *(const bf16x8*)((char*)sVT + rr * 256 + (cbb ^ ((rr & 7) << 4)));
            #pragma unroll
            for (int rt = 0; rt < 2; ++rt)
                o[rt][ct] = __builtin_amdgcn_mfma_f32_16x16x32_bf16(aP[rt], bV, o[rt][ct], 0, 0, 0);
        }
    }
    #pragma unroll
    for (int rt = 0; rt < 2; ++rt)
        #pragma unroll
        for (int ct = 0; ct < 2; ++ct)
            #pragma unroll
            for (int r = 0; r < 4; ++r) {
                int n = mrow + rt * 16 + quad * 4 + r;
                out[((long)(wi * 128 + n)) * CDIM + h * 32 + ct * 16 + colb] =
                    __float2bfloat16(o[rt][ct][r]);
            }
}

// ---------------------------------------------------------------------------
extern "C" void kernel_launch(void* const* d_in, const int* in_sizes, int n_in,
                              void* d_out, int out_size, void* d_ws, size_t ws_size,
                              hipStream_t stream) {
    const float* x      = (const float*)d_in[0];
    const float* n1g    = (const float*)d_in[1];
    const float* n1b    = (const float*)d_in[2];
    const float* qkv_w  = (const float*)d_in[3];
    const float* qkv_b  = (const float*)d_in[4];
    const float* btab   = (const float*)d_in[5];
    const float* proj_w = (const float*)d_in[6];
    const float* proj_b = (const float*)d_in[7];
    const float* n2g    = (const float*)d_in[8];
    const float* n2b    = (const float*)d_in[9];
    const float* fc1_w  = (const float*)d_in[10];
    const float* fc1_b  = (const float*)d_in[11];
    const float* fc2_w  = (const float*)d_in[12];
    const float* fc2_b  = (const float*)d_in[13];
    float* outp = (float*)d_out;

    char* ws = (char*)d_ws;

    // ---- bf16 weight copies + expanded bias table at front of workspace ---
    const int NQKV = 576 * 192, NPROJ = 192 * 192, NFC1 = 768 * 192, NFC2 = 192 * 768;
    bf16* qkvW = (bf16*)ws;
    bf16* projW = qkvW + NQKV;
    bf16* fc1W = projW + NPROJ;
    bf16* fc2W = fc1W + NFC1;
    const size_t WBYTES = (size_t)(NQKV + NPROJ + NFC1 + NFC2) * 2;  // 884736
    float* bias6 = (float*)(ws + WBYTES);                            // 6*128*128 f32
    const size_t BBYTES = 6UL * 128 * 128 * 4;                       // 393216

    cvt_w_kernel<<<NQKV / 2048, 256, 0, stream>>>(qkv_w, qkvW, NQKV);
    cvt_w_kernel<<<NPROJ / 2048, 256, 0, stream>>>(proj_w, projW, NPROJ);
    cvt_w_kernel<<<NFC1 / 2048, 256, 0, stream>>>(fc1_w, fc1W, NFC1);
    cvt_w_kernel<<<NFC2 / 2048, 256, 0, stream>>>(fc2_w, fc2W, NFC2);
    bias_expand_kernel<<<64, 256, 0, stream>>>(btab, bias6);

    // ---- slab sizing: keep all intermediates L3-resident ------------------
    const size_t per_win = 6UL * 128 * 192 * 2;   // 294912 B per window
    size_t avail = ws_size > WBYTES + BBYTES ? ws_size - WBYTES - BBYTES : 0;
    int S = 512;
    while (S > 64 && (size_t)S * per_win > avail) S >>= 1;

    char* slots = ws + WBYTES + BBYTES;
    const size_t SLOT = (size_t)S * 128 * CDIM * 2;   // bytes per slot
    bf16* bufA = (bf16*)(slots);               // ln1 out -> attn_out -> xn2
    bf16* qb   = (bf16*)(slots + SLOT);        // q -> x2
    bf16* kb   = (bf16*)(slots + 2 * SLOT);    // k -> h1 (4 slots: 2..5)
    bf16* vb   = (bf16*)(slots + 3 * SLOT);    // v (transposed)
    bf16* x2   = qb;
    bf16* h1   = kb;

    for (int s0 = 0; s0 < N_WINDOWS; s0 += S) {
        ln_kernel<true, float><<<S * 32, 256, 0, stream>>>(x, n1g, n1b, bufA, s0);
        gemm_bt<EpiQKV><<<S * 9, 256, 0, stream>>>(bufA, qkvW, 192, 9, EpiQKV{qkv_b, qb, kb, vb});
        attn_kernel<<<S * 6, 256, 0, stream>>>(qb, kb, vb, bias6, bufA);
        gemm_bt<EpiProj><<<S * 3, 256, 0, stream>>>(bufA, projW, 192, 3, EpiProj{proj_b, x, x2, s0});
        ln_kernel<false, bf16><<<S * 32, 256, 0, stream>>>(x2, n2g, n2b, bufA, 0);
        gemm_bt<EpiGelu><<<S * 12, 256, 0, stream>>>(bufA, fc1W, 192, 12, EpiGelu{fc1_b, h1});
        gemm_bt<EpiOut><<<S * 3, 256, 0, stream>>>(h1, fc2W, 768, 3, EpiOut{fc2_b, x2, outp, s0});
    }
}